// Round 3
// baseline (3630.854 us; speedup 1.0000x reference)
//
#include <hip/hip_runtime.h>

constexpr int B_ = 128, S_ = 25, NF_ = 196, ENC_ = 512, ATT_ = 512;
constexpr int H_ = 512, E_ = 256, V_ = 10000, G4_ = 2048;
constexpr int VPAD_ = 10112;  // 79*128

typedef __attribute__((ext_vector_type(8))) __bf16 bf16x8;
typedef __attribute__((ext_vector_type(4))) __bf16 bf16x4;
typedef __attribute__((ext_vector_type(4))) float f32x4;

__device__ __forceinline__ float bflo(unsigned u) {
    return __builtin_bit_cast(float, u << 16);
}
__device__ __forceinline__ float bfhi(unsigned u) {
    return __builtin_bit_cast(float, u & 0xffff0000u);
}
__device__ __forceinline__ float fast_tanhf(float x) {
    x = fminf(fmaxf(x, -15.f), 15.f);
    return 1.f - 2.f * __fdividef(1.f, __expf(2.f * x) + 1.f);
}
__device__ __forceinline__ float fast_sigf(float x) {
    x = fminf(fmaxf(x, -30.f), 30.f);
    return __fdividef(1.f, 1.f + __expf(-x));
}

// ---------------- software grid barrier (all 256 blocks co-resident) ----------------
__device__ __forceinline__ void gridbar(int* bar, int idx) {
    __syncthreads();              // drains vmcnt: all block stores are in L2
    if (threadIdx.x == 0) {
        __threadfence();          // agent release: L2 writeback to coherence point
        atomicAdd(&bar[idx], 1);
        while (__hip_atomic_load(&bar[idx], __ATOMIC_ACQUIRE, __HIP_MEMORY_SCOPE_AGENT) < 256) {
            __builtin_amdgcn_s_sleep(1);
        }
    }
    __syncthreads();
}

// ---------------- setup kernels ----------------
__global__ __launch_bounds__(128) void k_zero(int* bar) { bar[threadIdx.x] = 0; }

__global__ __launch_bounds__(256) void k_cvt(const float* __restrict__ s,
                                             __bf16* __restrict__ d, int n4) {
    int i = blockIdx.x * 256 + threadIdx.x;
    if (i >= n4) return;
    float4 v = *(const float4*)&s[(size_t)i * 4];
    bf16x4 o;
    o[0] = (__bf16)v.x; o[1] = (__bf16)v.y; o[2] = (__bf16)v.z; o[3] = (__bf16)v.w;
    *(bf16x4*)&d[(size_t)i * 4] = o;
}

__global__ __launch_bounds__(256) void k_cvt_fcw(const float* __restrict__ s,
                                                 __bf16* __restrict__ d) {
    int i = blockIdx.x * 256 + threadIdx.x;
    if (i >= VPAD_ * 512 / 4) return;
    int e = i * 4;
    int row = e >> 9;
    bf16x4 o;
    if (row < V_) {
        float4 v = *(const float4*)&s[(size_t)row * 512 + (e & 511)];
        o[0] = (__bf16)v.x; o[1] = (__bf16)v.y; o[2] = (__bf16)v.z; o[3] = (__bf16)v.w;
    } else {
        o[0] = o[1] = o[2] = o[3] = (__bf16)0.f;
    }
    *(bf16x4*)&d[(size_t)e] = o;
}

// Ww[j][k] f32 -> W2[k][jp] u32 = pack(bf16 Ww[2jp][k], bf16 Ww[2jp+1][k])
__global__ __launch_bounds__(256) void k_pack_ww(const float* __restrict__ Ww,
                                                 unsigned* __restrict__ W2) {
    __shared__ float Ts[32][65];
    int t = threadIdx.x;
    int k0 = blockIdx.x * 32, j0 = blockIdx.y * 64;
    int c = t & 31, rr = t >> 5;
#pragma unroll
    for (int i = 0; i < 8; ++i) {
        int j = j0 + rr + i * 8;
        Ts[c][rr + i * 8] = Ww[(size_t)j * 512 + k0 + c];
    }
    __syncthreads();
#pragma unroll
    for (int i = 0; i < 4; ++i) {
        int kr = (t >> 5) + i * 8;
        int jc = t & 31;
        __bf16 b0 = (__bf16)Ts[kr][2 * jc], b1 = (__bf16)Ts[kr][2 * jc + 1];
        unsigned u = (unsigned)__builtin_bit_cast(unsigned short, b0)
                   | ((unsigned)__builtin_bit_cast(unsigned short, b1) << 16);
        W2[(size_t)(k0 + kr) * 256 + (j0 >> 1) + jc] = u;
    }
}

// W_ih[:, :256] -> contiguous bf16 [2048][256]
__global__ __launch_bounds__(256) void k_cvt_wih(const float* __restrict__ W_ih,
                                                 __bf16* __restrict__ o) {
    int n = blockIdx.x, k = threadIdx.x;
    o[(size_t)n * 256 + k] = (__bf16)W_ih[(size_t)n * 768 + k];
}

__global__ __launch_bounds__(256) void k_embed(const int* __restrict__ dec,
                                               const float* __restrict__ emb,
                                               const float* __restrict__ pose,
                                               __bf16* __restrict__ out) {
    int bx = blockIdx.x;
    int s = bx >> 7, b = bx & 127;
    int e = threadIdx.x;
    int tok = dec[b * S_ + s];
    out[(size_t)bx * E_ + e] = (__bf16)(emb[tok * E_ + e] + pose[s * E_ + e]);
}

__global__ __launch_bounds__(256) void k_init(const float* __restrict__ enc,
                                              const float* __restrict__ ihw, const float* __restrict__ ihb,
                                              const float* __restrict__ icw, const float* __restrict__ icb,
                                              float* __restrict__ Hall, float* __restrict__ cbuf) {
    __shared__ __align__(16) float mean[ENC_];
    int b = blockIdx.x, t = threadIdx.x;
    for (int d = t; d < ENC_; d += 256) {
        float sum = 0.f;
        for (int n = 0; n < NF_; ++n) sum += enc[(b * NF_ + n) * ENC_ + d];
        mean[d] = sum * (1.f / NF_);
    }
    __syncthreads();
    for (int j = t; j < H_; j += 256) {
        float ah = 0.f, ac = 0.f;
        const float4* wh = (const float4*)&ihw[j * ENC_];
        const float4* wc = (const float4*)&icw[j * ENC_];
        for (int d4 = 0; d4 < ENC_ / 4; ++d4) {
            float4 m4 = *(const float4*)&mean[d4 * 4];
            float4 h4 = wh[d4], c4 = wc[d4];
            ah += m4.x * h4.x + m4.y * h4.y + m4.z * h4.z + m4.w * h4.w;
            ac += m4.x * c4.x + m4.y * c4.y + m4.z * c4.z + m4.w * c4.w;
        }
        Hall[b * H_ + j] = ah + ihb[j];
        cbuf[b * H_ + j] = ac + icb[j];
    }
}

// ---------------- bf16 MFMA GEMM ----------------
// MODE 0: f32 out, remap row, guard n<Nreal, +bias1 (fcn)
// MODE 1: bf16 out, +bias1 (u_hs)
// MODE 2: f32 out, +bias1+bias2 (gates_pre)
template<int MODE>
__global__ __launch_bounds__(256) void k_mfma_gemm(
    const __bf16* __restrict__ A, const __bf16* __restrict__ Bm,
    const float* __restrict__ bias1, const float* __restrict__ bias2,
    void* __restrict__ Cout, int K, int Nreal, int ldc) {
    __shared__ __align__(16) __bf16 As[128 * 64];
    __shared__ __align__(16) __bf16 Bs[128 * 64];
    int tid = threadIdx.x;
    int lane = tid & 63, w = tid >> 6;
    int m0 = blockIdx.x * 128, n0 = blockIdx.y * 128;
    int wm = (w & 1) * 64, wn = (w >> 1) * 64;
    f32x4 acc[4][4] = {};
    int srow = tid >> 3;
    int ke = (tid & 7) * 8;
    int kgw = tid & 7;

    for (int k0 = 0; k0 < K; k0 += 64) {
#pragma unroll
        for (int it = 0; it < 4; ++it) {
            int row = it * 32 + srow;
            bf16x8 av = *(const bf16x8*)(A + (size_t)(m0 + row) * K + k0 + ke);
            bf16x8 bv = *(const bf16x8*)(Bm + (size_t)(n0 + row) * K + k0 + ke);
            int kg = kgw ^ (row & 7);
            *(bf16x8*)&As[row * 64 + kg * 8] = av;
            *(bf16x8*)&Bs[row * 64 + kg * 8] = bv;
        }
        __syncthreads();
        bf16x8 af[4][2], bfr[4][2];
#pragma unroll
        for (int f = 0; f < 4; ++f) {
#pragma unroll
            for (int ks = 0; ks < 2; ++ks) {
                int ra = wm + f * 16 + (lane & 15);
                int rb = wn + f * 16 + (lane & 15);
                int kgl = ks * 4 + (lane >> 4);
                af[f][ks]  = *(const bf16x8*)&As[ra * 64 + (kgl ^ (ra & 7)) * 8];
                bfr[f][ks] = *(const bf16x8*)&Bs[rb * 64 + (kgl ^ (rb & 7)) * 8];
            }
        }
#pragma unroll
        for (int fm = 0; fm < 4; ++fm)
#pragma unroll
            for (int fn = 0; fn < 4; ++fn)
#pragma unroll
                for (int ks = 0; ks < 2; ++ks)
                    acc[fm][fn] = __builtin_amdgcn_mfma_f32_16x16x32_bf16(
                        af[fm][ks], bfr[fn][ks], acc[fm][fn], 0, 0, 0);
        __syncthreads();
    }
    int cm = (lane >> 4) * 4, cn = lane & 15;
#pragma unroll
    for (int fm = 0; fm < 4; ++fm) {
#pragma unroll
        for (int fn = 0; fn < 4; ++fn) {
#pragma unroll
            for (int r = 0; r < 4; ++r) {
                int gm = m0 + wm + fm * 16 + cm + r;
                int gn = n0 + wn + fn * 16 + cn;
                float v = acc[fm][fn][r];
                if (MODE == 0) {
                    if (gn < Nreal) {
                        int orow = (gm & 127) * S_ + (gm >> 7);
                        ((float*)Cout)[(size_t)orow * ldc + gn] = v + bias1[gn];
                    }
                } else if (MODE == 1) {
                    ((__bf16*)Cout)[(size_t)gm * ldc + gn] = (__bf16)(v + bias1[gn]);
                } else {
                    ((float*)Cout)[(size_t)gm * ldc + gn] = v + bias1[gn] + bias2[gn];
                }
            }
        }
    }
}

// ---------------- persistent recurrence megakernel: 256 blocks, 75 grid barriers ----------------
__global__ __launch_bounds__(256) void k_steps(
    const __bf16* __restrict__ u_hs,      // [25088][512]
    const unsigned* __restrict__ enc2,    // enc bf16 pairs [25088][256]
    const unsigned* __restrict__ W2,      // [512][256] packed Ww^T
    const float* __restrict__ Wb,
    const float* __restrict__ Aw,
    const float* __restrict__ W_ih,       // [2048][768]
    const float* __restrict__ W_hh,       // [2048][512]
    const float* __restrict__ gatespre,   // [3200][2048]
    float* __restrict__ Hall,             // [26][128][512]
    __bf16* __restrict__ Hall_bf,
    float* __restrict__ cbuf,
    float* __restrict__ sc_g,             // [128][196]
    float* __restrict__ ctxp,             // [2][128][512]
    float* __restrict__ alphas,           // -> out+32000000
    int* __restrict__ bar) {
    int bid = blockIdx.x, t = threadIdx.x;
    __shared__ float hs[512], wah[512], awS[512];
    __shared__ float red[256];
    __shared__ float al[98];
    __shared__ float As[64][34];
    __shared__ float Bs[64][34];

    awS[t] = Aw[t]; awS[t + 256] = Aw[t + 256];

    int b2 = bid >> 1, nh = bid & 1;              // phases A,B
    int b0 = (bid & 3) * 32, j0 = (bid >> 2) * 8; // phase C
    int tm = (t >> 4) * 2, tn = (t & 15) * 2;
    int r = t >> 3, kq = (t & 7) * 8;
    int wr = (r >> 3) * 512 + j0 + (r & 7);

    for (int s = 0; s < S_; ++s) {
        // ========== Phase A: w_ah (coalesced packed W2) + scores ==========
        {
            float2 h2v = *(const float2*)&Hall[(size_t)s * 65536 + b2 * 512 + t * 2];
            hs[t * 2] = h2v.x; hs[t * 2 + 1] = h2v.y;
            __syncthreads();
            float a0 = Wb[2 * t], a1 = Wb[2 * t + 1];
#pragma unroll 2
            for (int k4 = 0; k4 < 128; ++k4) {
                float4 hk = *(const float4*)&hs[k4 * 4];
                unsigned w0 = W2[(k4 * 4 + 0) * 256 + t];
                unsigned w1 = W2[(k4 * 4 + 1) * 256 + t];
                unsigned w2 = W2[(k4 * 4 + 2) * 256 + t];
                unsigned w3 = W2[(k4 * 4 + 3) * 256 + t];
                a0 += hk.x * bflo(w0); a1 += hk.x * bfhi(w0);
                a0 += hk.y * bflo(w1); a1 += hk.y * bfhi(w1);
                a0 += hk.z * bflo(w2); a1 += hk.z * bfhi(w2);
                a0 += hk.w * bflo(w3); a1 += hk.w * bfhi(w3);
            }
            wah[2 * t] = a0; wah[2 * t + 1] = a1;
            __syncthreads();
            int w = t >> 6, ln = t & 63;
            int ji = ln * 8;
            for (int n0 = w; n0 < 98; n0 += 4) {
                int n = nh * 98 + n0;
                bf16x8 u8 = *(const bf16x8*)&u_hs[((size_t)(b2 * 196 + n)) * 512 + ji];
                float acc = 0.f;
#pragma unroll
                for (int i = 0; i < 8; ++i)
                    acc += fast_tanhf((float)u8[i] + wah[ji + i]) * awS[ji + i];
#pragma unroll
                for (int off = 32; off; off >>= 1) acc += __shfl_xor(acc, off);
                if (ln == 0) sc_g[b2 * 196 + n] = acc;   // Ab omitted: cancels in softmax
            }
        }
        gridbar(bar, s * 3 + 0);
        // ========== Phase B: softmax + ctx partials ==========
        {
            float v = (t < 196) ? sc_g[b2 * 196 + t] : -1e30f;
            red[t] = v; __syncthreads();
#pragma unroll
            for (int off = 128; off; off >>= 1) {
                if (t < off) red[t] = fmaxf(red[t], red[t + off]);
                __syncthreads();
            }
            float mx = red[0]; __syncthreads();
            float e = (t < 196) ? __expf(v - mx) : 0.f;
            red[t] = e; __syncthreads();
#pragma unroll
            for (int off = 128; off; off >>= 1) {
                if (t < off) red[t] += red[t + off];
                __syncthreads();
            }
            float inv = __fdividef(1.f, red[0]);
            float a = e * inv;
            if (t < 196 && nh == 0) alphas[((size_t)b2 * 25 + s) * 196 + t] = a;
            int tl = t - nh * 98;
            if (tl >= 0 && tl < 98) al[tl] = a;
            __syncthreads();
            const unsigned* ebase = enc2 + ((size_t)(b2 * 196 + nh * 98)) * 256 + t;
            float c0 = 0.f, c1 = 0.f;
#pragma unroll 7
            for (int i = 0; i < 98; ++i) {
                unsigned e2 = ebase[(size_t)i * 256];
                c0 += al[i] * bflo(e2);
                c1 += al[i] * bfhi(e2);
            }
            float* cp = &ctxp[((size_t)(nh * 128 + b2)) * 512 + 2 * t];
            cp[0] = c0; cp[1] = c1;
        }
        gridbar(bar, s * 3 + 1);
        // ========== Phase C: gates GEMM (K=1024) + LSTM pointwise ==========
        {
            float a00 = 0.f, a01 = 0.f, a10 = 0.f, a11 = 0.f;
            for (int k0 = 0; k0 < 1024; k0 += 64) {
                if (k0 < 512) {
                    const float* p0 = &ctxp[(size_t)(b0 + r) * 512 + k0 + kq];
                    const float* p1 = p0 + 128 * 512;
                    float4 x0 = *(const float4*)p0, x1 = *(const float4*)(p0 + 4);
                    float4 y0 = *(const float4*)p1, y1 = *(const float4*)(p1 + 4);
                    As[kq + 0][r] = x0.x + y0.x; As[kq + 1][r] = x0.y + y0.y;
                    As[kq + 2][r] = x0.z + y0.z; As[kq + 3][r] = x0.w + y0.w;
                    As[kq + 4][r] = x1.x + y1.x; As[kq + 5][r] = x1.y + y1.y;
                    As[kq + 6][r] = x1.z + y1.z; As[kq + 7][r] = x1.w + y1.w;
                } else {
                    const float* p0 = &Hall[(size_t)s * 65536 + (b0 + r) * 512 + (k0 - 512) + kq];
                    float4 x0 = *(const float4*)p0, x1 = *(const float4*)(p0 + 4);
                    As[kq + 0][r] = x0.x; As[kq + 1][r] = x0.y;
                    As[kq + 2][r] = x0.z; As[kq + 3][r] = x0.w;
                    As[kq + 4][r] = x1.x; As[kq + 5][r] = x1.y;
                    As[kq + 6][r] = x1.z; As[kq + 7][r] = x1.w;
                }
                const float* bp = (k0 < 512) ? &W_ih[(size_t)wr * 768 + 256 + k0 + kq]
                                             : &W_hh[(size_t)wr * 512 + (k0 - 512) + kq];
                float4 b0v = *(const float4*)bp, b1v = *(const float4*)(bp + 4);
                Bs[kq + 0][r] = b0v.x; Bs[kq + 1][r] = b0v.y;
                Bs[kq + 2][r] = b0v.z; Bs[kq + 3][r] = b0v.w;
                Bs[kq + 4][r] = b1v.x; Bs[kq + 5][r] = b1v.y;
                Bs[kq + 6][r] = b1v.z; Bs[kq + 7][r] = b1v.w;
                __syncthreads();
#pragma unroll
                for (int kk = 0; kk < 64; ++kk) {
                    float2 a2 = *(const float2*)&As[kk][tm];
                    float2 bb = *(const float2*)&Bs[kk][tn];
                    a00 += a2.x * bb.x; a01 += a2.x * bb.y;
                    a10 += a2.y * bb.x; a11 += a2.y * bb.y;
                }
                __syncthreads();
            }
            float (*Gs)[34] = As;
            Gs[tm][tn] = a00; Gs[tm][tn + 1] = a01;
            Gs[tm + 1][tn] = a10; Gs[tm + 1][tn + 1] = a11;
            __syncthreads();
            int bl = t >> 3, jj = t & 7;
            int gb = b0 + bl, gj = j0 + jj;
            float q[4];
#pragma unroll
            for (int g = 0; g < 4; ++g)
                q[g] = Gs[bl][g * 8 + jj] + gatespre[((size_t)s * 128 + gb) * 2048 + g * 512 + gj];
            float ig = fast_sigf(q[0]), fg = fast_sigf(q[1]);
            float gg = fast_tanhf(q[2]), og = fast_sigf(q[3]);
            int ci = gb * 512 + gj;
            float cn = fg * cbuf[ci] + ig * gg;
            float hn = og * fast_tanhf(cn);
            cbuf[ci] = cn;
            Hall[(size_t)(s + 1) * 65536 + ci] = hn;
            Hall_bf[(size_t)(s + 1) * 65536 + ci] = (__bf16)hn;
        }
        gridbar(bar, s * 3 + 2);
    }
}

extern "C" void kernel_launch(void* const* d_in, const int* in_sizes, int n_in,
                              void* d_out, int out_size, void* d_ws, size_t ws_size,
                              hipStream_t stream) {
    const int*   dec  = (const int*)d_in[0];
    const float* enc  = (const float*)d_in[1];
    const float* emb  = (const float*)d_in[2];
    const float* pose = (const float*)d_in[3];
    const float* Uw   = (const float*)d_in[4];
    const float* Ub   = (const float*)d_in[5];
    const float* Ww   = (const float*)d_in[6];
    const float* Wb   = (const float*)d_in[7];
    const float* Aw   = (const float*)d_in[8];
    // d_in[9] = Ab: cancels in softmax, unused
    const float* ihw  = (const float*)d_in[10];
    const float* ihb  = (const float*)d_in[11];
    const float* icw  = (const float*)d_in[12];
    const float* icb  = (const float*)d_in[13];
    const float* W_ih = (const float*)d_in[14];
    const float* W_hh = (const float*)d_in[15];
    const float* b_ih = (const float*)d_in[16];
    const float* b_hh = (const float*)d_in[17];
    const float* fcw  = (const float*)d_in[18];
    const float* fcb  = (const float*)d_in[19];
    float* out = (float*)d_out;
    char*  wsb = (char*)d_ws;

    // ---- workspace layout (bytes), ~92.5 MB; fcw_bf aliases enc_bf (dead after k_steps) ----
    size_t o = 0;
    __bf16*   enc_bf   = (__bf16*)(wsb + o);
    __bf16*   fcw_bf   = (__bf16*)(wsb + o); o += (size_t)25088 * 512 * 2;  // 25,690,112
    __bf16*   u_hs_bf  = (__bf16*)(wsb + o); o += (size_t)25088 * 512 * 2;  // 25,690,112
    float*    gatespre = (float*)(wsb + o);  o += (size_t)3200 * 2048 * 4;  // 26,214,400
    float*    Hall     = (float*)(wsb + o);  o += (size_t)26 * 65536 * 4;   //  6,815,744
    __bf16*   Hall_bf  = (__bf16*)(wsb + o); o += (size_t)26 * 65536 * 2;   //  3,407,872
    float*    cbuf     = (float*)(wsb + o);  o += (size_t)65536 * 4;        //    262,144
    float*    sc_g     = (float*)(wsb + o);  o += (size_t)128 * 196 * 4;    //    100,352
    float*    ctxp     = (float*)(wsb + o);  o += (size_t)2 * 65536 * 4;    //    524,288
    __bf16*   Uw_bf    = (__bf16*)(wsb + o); o += (size_t)262144 * 2;       //    524,288
    unsigned* W2       = (unsigned*)(wsb + o); o += (size_t)512 * 256 * 4;  //    524,288
    __bf16*   WihE_bf  = (__bf16*)(wsb + o); o += (size_t)2048 * 256 * 2;   //  1,048,576
    __bf16*   embeds_bf= (__bf16*)(wsb + o); o += (size_t)3200 * 256 * 2;   //  1,638,400
    int*      bar      = (int*)(wsb + o);    o += 512;

    // ---- setup ----
    k_zero<<<1, 128, 0, stream>>>(bar);
    k_cvt<<<12544, 256, 0, stream>>>(enc, enc_bf, 3211264);
    k_cvt<<<256, 256, 0, stream>>>(Uw, Uw_bf, 65536);
    k_pack_ww<<<dim3(16, 8), 256, 0, stream>>>(Ww, W2);
    k_cvt_wih<<<2048, 256, 0, stream>>>(W_ih, WihE_bf);
    k_embed<<<S_ * B_, 256, 0, stream>>>(dec, emb, pose, embeds_bf);
    k_init<<<B_, 256, 0, stream>>>(enc, ihw, ihb, icw, icb, Hall, cbuf);

    // u_hs = enc @ Uw^T + Ub -> bf16 [25088,512]
    k_mfma_gemm<1><<<dim3(196, 4), 256, 0, stream>>>(enc_bf, Uw_bf, Ub, nullptr,
                                                     u_hs_bf, 512, 512, 512);
    // gates_pre = embeds @ W_ih[:, :256]^T + b_ih + b_hh -> f32 [3200,2048]
    k_mfma_gemm<2><<<dim3(25, 16), 256, 0, stream>>>(embeds_bf, WihE_bf, b_ih, b_hh,
                                                     gatespre, 256, 2048, 2048);

    // ---- the whole 25-step recurrence in one persistent kernel ----
    k_steps<<<256, 256, 0, stream>>>(u_hs_bf, (const unsigned*)enc_bf, W2, Wb, Aw,
                                     W_ih, W_hh, gatespre, Hall, Hall_bf, cbuf,
                                     sc_g, ctxp, out + 32000000, bar);

    // fcw -> bf16 (aliases enc_bf region, dead after k_steps)
    k_cvt_fcw<<<5056, 256, 0, stream>>>(fcw, fcw_bf);
    // outs = Hall_bf[1..25] @ fcn_w^T + fcn_b -> f32 [B,S,V]
    k_mfma_gemm<0><<<dim3(25, 79), 256, 0, stream>>>(Hall_bf + 65536, fcw_bf, fcb, nullptr,
                                                     out, 512, V_, V_);
}